// Round 5
// baseline (593.697 us; speedup 1.0000x reference)
//
#include <hip/hip_runtime.h>
#include <cstdint>
#include <cstddef>

typedef _Float16 half8 __attribute__((ext_vector_type(8)));
typedef _Float16 half4 __attribute__((ext_vector_type(4)));
typedef float f32x4 __attribute__((ext_vector_type(4)));

// async global->LDS, 16B per lane; LDS dest must be wave-uniform base + lane*16
#define GLDS16(g, l) __builtin_amdgcn_global_load_lds( \
    (__attribute__((address_space(1))) void*)(g), \
    (__attribute__((address_space(3))) void*)(l), 16, 0, 0)

// ---------------------------------------------------------------------------
// fp32 -> fp16 convert
// ---------------------------------------------------------------------------
__global__ __launch_bounds__(256) void cvt_f32_f16(const float* __restrict__ src,
                                                   _Float16* __restrict__ dst, int n) {
  int i = (blockIdx.x * 256 + threadIdx.x) * 8;
  if (i >= n) return;
  float4 a = *(const float4*)(src + i);
  float4 b = *(const float4*)(src + i + 4);
  half8 h;
  h[0] = (_Float16)a.x; h[1] = (_Float16)a.y; h[2] = (_Float16)a.z; h[3] = (_Float16)a.w;
  h[4] = (_Float16)b.x; h[5] = (_Float16)b.y; h[6] = (_Float16)b.z; h[7] = (_Float16)b.w;
  *(half8*)(dst + i) = h;
}

// ---------------------------------------------------------------------------
// GEMM C[m,n] = sum_k A[m,k]*Bw[n,k] (+bias).  A fp16 MxK, Bw fp16 NxK, K=512.
// 128x128 tile, BK=64 (8 iters, 32 MFMA per wave per barrier-pair).
// LDS in MFMA fragment order: within each 16-row band, 16B chunk (row r,
// k-chunk c) at slot c*16+r  ->  fragment ds_read_b128 = band_base + lane*16.
// ---------------------------------------------------------------------------
template<int NOUT, int NT, bool BIAS>
__global__ __launch_bounds__(256, 3) void gemm_bt(const _Float16* __restrict__ A,
                                                  const _Float16* __restrict__ Bw,
                                                  const float* __restrict__ bias,
                                                  void* __restrict__ Cout) {
  constexpr int K = 512;
  __shared__ union {
    struct { _Float16 As[8192]; _Float16 Bs[8192]; } s;  // fragment-order 128x64 tiles
    float E[2][16][132];                                  // epilogue staging
  } u;
  const int id  = blockIdx.x;
  const int xcd = id & 7;                 // XCD cohort: N-tiles of a band share L2
  const int jj  = id >> 3;
  const int by  = (jj / NT) * 8 + xcd;
  const int bx  = jj % NT;
  const int m_base = by * 128, n_base = bx * 128;

  const int t    = threadIdx.x;
  const int lane = t & 63;
  const int wid  = t >> 6;
  const int wm   = wid >> 1, wn = wid & 1;
  const int cl   = lane & 15, q = lane >> 4;

  f32x4 acc[4][4] = {};

  // staging: 1024 16B-chunks per tile, 4 per thread.
  // slot s -> band = s>>7 (16 rows), k-chunk c = (s>>4)&7, row r = s&15
  const _Float16* aS[4]; const _Float16* bS[4];
  char* aD[4]; char* bD[4];
#pragma unroll
  for (int j = 0; j < 4; j++) {
    const int s = t + j * 256;
    const int r = ((s >> 7) << 4) | (s & 15);
    const int c = (s >> 4) & 7;
    aS[j] = A  + (size_t)(m_base + r) * K + c * 8;
    bS[j] = Bw + (size_t)(n_base + r) * K + c * 8;
    aD[j] = (char*)u.s.As + s * 16;
    bD[j] = (char*)u.s.Bs + s * 16;
  }

  const int lane8 = lane * 8;   // fragment offset in halves within a band

  for (int k0 = 0; k0 < K; k0 += 64) {
#pragma unroll
    for (int j = 0; j < 4; j++) GLDS16(aS[j] + k0, aD[j]);
#pragma unroll
    for (int j = 0; j < 4; j++) GLDS16(bS[j] + k0, bD[j]);
    __syncthreads();   // drains vmcnt for global_load_lds
#pragma unroll
    for (int kk = 0; kk < 2; kk++) {
      half8 af[4], bf[4];
#pragma unroll
      for (int i = 0; i < 4; i++)
        af[i] = *(const half8*)(u.s.As + (wm * 4 + i) * 1024 + kk * 512 + lane8);
#pragma unroll
      for (int i = 0; i < 4; i++)
        bf[i] = *(const half8*)(u.s.Bs + (wn * 4 + i) * 1024 + kk * 512 + lane8);
#pragma unroll
      for (int mt = 0; mt < 4; mt++)
#pragma unroll
        for (int nt = 0; nt < 4; nt++)
          acc[mt][nt] = __builtin_amdgcn_mfma_f32_16x16x32_f16(af[mt], bf[nt], acc[mt][nt], 0, 0, 0);
    }
    __syncthreads();
  }

  // epilogue: C/D layout (row=q*4+r, col=lane&15) -> LDS -> group-aligned reads
  const int ebnd = t >> 7, erow = (t >> 3) & 15, ecs = t & 7;
#pragma unroll
  for (int mt = 0; mt < 4; mt++) {
#pragma unroll
    for (int nt = 0; nt < 4; nt++)
#pragma unroll
      for (int r = 0; r < 4; r++)
        u.E[wm][q * 4 + r][wn * 64 + nt * 16 + cl] = acc[mt][nt][r];
    __syncthreads();
    const size_t rg = (size_t)(m_base + ebnd * 64 + mt * 16 + erow);
#pragma unroll
    for (int j = 0; j < 4; j++) {
      // E row stride = 132 floats = 33 chunks -> chunk ((ecs-erow)&7)+8j keeps
      // bank group == lane&7
      const int ch = ((ecs - erow) & 7) + 8 * j;
      const int cc = ch * 4;
      float4 e = *(const float4*)&u.E[ebnd][erow][cc];
      if constexpr (BIAS) {
        const float4 bb = *(const float4*)(bias + n_base + cc);
        e.x += bb.x; e.y += bb.y; e.z += bb.z; e.w += bb.w;
        *(float4*)((float*)Cout + rg * NOUT + n_base + cc) = e;
      } else {
        half4 hv;
        hv[0] = (_Float16)e.x; hv[1] = (_Float16)e.y;
        hv[2] = (_Float16)e.z; hv[3] = (_Float16)e.w;
        *(half4*)((_Float16*)Cout + rg * NOUT + n_base + cc) = hv;
      }
    }
    __syncthreads();
  }
}

// ---------------------------------------------------------------------------
// Windowed attention: one block per (head h, window b). W=64, hd=64.
// ONE __syncthreads total: each wave owns 16 Q-rows end-to-end; softmax and
// the P/O LDS round-trips are wave-local (lgkmcnt waits only).
// ---------------------------------------------------------------------------
__global__ __launch_bounds__(256, 3) void attn_win(const _Float16* __restrict__ QKV,
                                                   _Float16* __restrict__ Out) {
  __shared__ _Float16 Qs[4096];     // fragment-order 64x64
  __shared__ _Float16 Ks[4096];     // fragment-order 64x64
  __shared__ _Float16 Vt[64][72];   // V transposed: Vt[e][j], padded rows
  __shared__ _Float16 Ps[4][1024];  // per-wave P strip (16x64, fragment order)
  __shared__ _Float16 Os[4][1024];  // per-wave O strip (16x64, row-major)
  const int h = blockIdx.x, b = blockIdx.y;
  const int t = threadIdx.x;
  const int lane = t & 63, wid = t >> 6;
  const int cl = lane & 15, q = lane >> 4;

  // ---- stage Q,K (async, fragment order) and V (manual transpose) ----
  {
    const int s0 = t, s1 = t + 256;
    const int r0 = ((s0 >> 7) << 4) | (s0 & 15), ch0 = (s0 >> 4) & 7;
    const int r1 = ((s1 >> 7) << 4) | (s1 & 15), ch1 = (s1 >> 4) & 7;
    const _Float16* g0 = QKV + (size_t)(b * 64 + r0) * 1536 + h * 64 + ch0 * 8;
    const _Float16* g1 = QKV + (size_t)(b * 64 + r1) * 1536 + h * 64 + ch1 * 8;
    GLDS16(g0,       (char*)Qs + s0 * 16);
    GLDS16(g1,       (char*)Qs + s1 * 16);
    GLDS16(g0 + 512, (char*)Ks + s0 * 16);
    GLDS16(g1 + 512, (char*)Ks + s1 * 16);

    const int vj = t & 63, vp = t >> 6;   // row j of V, 16-half chunk vp
    const _Float16* vsrc = QKV + (size_t)(b * 64 + vj) * 1536 + 1024 + h * 64 + vp * 16;
    half8 v0 = *(const half8*)vsrc;
    half8 v1 = *(const half8*)(vsrc + 8);
#pragma unroll
    for (int i = 0; i < 8; i++) Vt[vp * 16 + i][vj] = v0[i];
#pragma unroll
    for (int i = 0; i < 8; i++) Vt[vp * 16 + 8 + i][vj] = v1[i];
  }
  __syncthreads();   // the only block-wide barrier

  const int lane8 = lane * 8;

  // ---- S = Q K^T (wave's 16 rows = Q band wid) ----
  f32x4 s[4] = {};
#pragma unroll
  for (int ks = 0; ks < 2; ks++) {
    half8 a = *(const half8*)(Qs + wid * 1024 + ks * 512 + lane8);
#pragma unroll
    for (int nt = 0; nt < 4; nt++) {
      half8 bb = *(const half8*)(Ks + nt * 1024 + ks * 512 + lane8);
      s[nt] = __builtin_amdgcn_mfma_f32_16x16x32_f16(a, bb, s[nt], 0, 0, 0);
    }
  }

  // ---- softmax (wave-local; row=q*4+r, keys j=nt*16+cl) -> Ps strip ----
  constexpr float SC = 0.125f * 1.44269504088896340736f;  // scale * log2(e)
#pragma unroll
  for (int r = 0; r < 4; r++) {
    float mx = fmaxf(fmaxf(s[0][r], s[1][r]), fmaxf(s[2][r], s[3][r]));
    mx = fmaxf(mx, __shfl_xor(mx, 1));
    mx = fmaxf(mx, __shfl_xor(mx, 2));
    mx = fmaxf(mx, __shfl_xor(mx, 4));
    mx = fmaxf(mx, __shfl_xor(mx, 8));
    float e[4], ssum = 0.f;
#pragma unroll
    for (int nt = 0; nt < 4; nt++) { e[nt] = exp2f((s[nt][r] - mx) * SC); ssum += e[nt]; }
    ssum += __shfl_xor(ssum, 1);
    ssum += __shfl_xor(ssum, 2);
    ssum += __shfl_xor(ssum, 4);
    ssum += __shfl_xor(ssum, 8);
    float inv = 1.f / ssum;
#pragma unroll
    for (int nt = 0; nt < 4; nt++) {
      // fragment order: key j=nt*16+cl -> chunk c=j>>3, sub j&7; row=q*4+r
      const int idx = ((nt * 2 + (cl >> 3)) * 16 + q * 4 + r) * 8 + (cl & 7);
      Ps[wid][idx] = (_Float16)(e[nt] * inv);
    }
  }
  asm volatile("s_waitcnt lgkmcnt(0)" ::: "memory");  // wave-local P ready

  // ---- O = P V  (a: own P strip; b: Vt rows = V columns) ----
  f32x4 o[4] = {};
#pragma unroll
  for (int kk = 0; kk < 2; kk++) {
    half8 a = *(const half8*)(Ps[wid] + kk * 512 + lane8);
#pragma unroll
    for (int nt = 0; nt < 4; nt++) {
      half8 bb = *(const half8*)&Vt[nt * 16 + cl][kk * 32 + q * 8];
      o[nt] = __builtin_amdgcn_mfma_f32_16x16x32_f16(a, bb, o[nt], 0, 0, 0);
    }
  }
#pragma unroll
  for (int nt = 0; nt < 4; nt++)
#pragma unroll
    for (int r = 0; r < 4; r++)
      Os[wid][(q * 4 + r) * 64 + nt * 16 + cl] = (_Float16)o[nt][r];
  asm volatile("s_waitcnt lgkmcnt(0)" ::: "memory");  // wave-local O ready

  // ---- coalesced write-out (wave-local strip) ----
  {
    const int row = lane >> 2, cs = lane & 3;
    const _Float16* sp = Os[wid] + row * 64 + cs * 16;
    half8 h0 = *(const half8*)sp;
    half8 h1 = *(const half8*)(sp + 8);
    _Float16* dst = Out + (size_t)(b * 64 + wid * 16 + row) * 512 + h * 64 + cs * 16;
    *(half8*)dst = h0;
    *((half8*)dst + 1) = h1;
  }
}

// ---------------------------------------------------------------------------
extern "C" void kernel_launch(void* const* d_in, const int* in_sizes, int n_in,
                              void* d_out, int out_size, void* d_ws, size_t ws_size,
                              hipStream_t stream) {
  const float* x      = (const float*)d_in[0];   // 16*4096*512
  const float* qkv_w  = (const float*)d_in[1];   // 1536*512
  const float* proj_w = (const float*)d_in[2];   // 512*512
  const float* proj_b = (const float*)d_in[3];   // 512
  float* out = (float*)d_out;

  char* ws = (char*)d_ws;
  _Float16* QKVh = (_Float16*)ws;                 // 65536*1536 fp16 = 201,326,592 B
  _Float16* Xh   = (_Float16*)(ws + 201326592);   // 65536*512 fp16 = 67,108,864 B
  _Float16* Outh = Xh;                            // alias: Xh dead after qkv_gemm
  _Float16* Wq   = (_Float16*)(ws + 268435456);   // 1536*512 fp16
  _Float16* Wp   = (_Float16*)(ws + 270008320);   // 512*512 fp16

  cvt_f32_f16<<<16384, 256, 0, stream>>>(x, Xh, 16 * 4096 * 512);
  cvt_f32_f16<<<384, 256, 0, stream>>>(qkv_w, Wq, 1536 * 512);
  cvt_f32_f16<<<128, 256, 0, stream>>>(proj_w, Wp, 512 * 512);
  gemm_bt<1536, 12, false><<<6144, 256, 0, stream>>>(Xh, Wq, nullptr, QKVh);
  attn_win<<<dim3(8, 1024), 256, 0, stream>>>(QKVh, Outh);
  gemm_bt<512, 4, true><<<2048, 256, 0, stream>>>(Outh, Wp, proj_b, out);
}